// Round 1
// baseline (1223.999 us; speedup 1.0000x reference)
//
#include <hip/hip_runtime.h>

// DualEmbedding fused kernels for MI355X (gfx950).
// Kernel A: h_node = x_node @ W_node.T + b_node   -> d_ws  [N,128]
// Kernel B: out = LN(x_edge @ W_edge.T + b_edge + 0.5*(h_node[src]+h_node[dst]))
//
// Design: one wave (64 lanes) per row. Lane l owns output dims {l, l+64}
// (kernel B) or dim half*64+l (kernel A). Weight rows live in VGPRs across a
// grid-strided row loop; per-row activations are wave-uniform -> scalar loads
// (s_load) feed v_fmac directly. LayerNorm via __shfl_xor wave reductions.

__device__ __forceinline__ float wave_sum64(float x) {
#pragma unroll
  for (int off = 32; off > 0; off >>= 1) x += __shfl_xor(x, off, 64);
  return x;
}

__global__ __launch_bounds__(256) void node_proj_kernel(
    const float* __restrict__ x_node,
    const float* __restrict__ W_node,
    const float* __restrict__ b_node,
    float* __restrict__ h_node,
    int n_nodes)
{
  const int lane = threadIdx.x & 63;
  const int wid  = __builtin_amdgcn_readfirstlane((int)(threadIdx.x >> 6));
  const int gw = blockIdx.x * 4 + wid;          // global wave id (uniform)
  const int nw = gridDim.x * 4;
  const int half = gw & 1;                      // which 64-dim half this wave does
  const int d = half * 64 + lane;               // this lane's output dim

  // W_node row d -> 128 floats in VGPRs (32 x float4)
  float4 w[32];
  const float4* wp = (const float4*)(W_node + (size_t)d * 128);
#pragma unroll
  for (int i = 0; i < 32; ++i) w[i] = wp[i];
  const float bias = b_node[d];

  for (int node = gw >> 1; node < n_nodes; node += (nw >> 1)) {
    const float* xr = x_node + (size_t)node * 128;   // uniform -> s_load
    float acc = bias;
#pragma unroll
    for (int i = 0; i < 32; ++i) {
      acc = fmaf(w[i].x, xr[4 * i + 0], acc);
      acc = fmaf(w[i].y, xr[4 * i + 1], acc);
      acc = fmaf(w[i].z, xr[4 * i + 2], acc);
      acc = fmaf(w[i].w, xr[4 * i + 3], acc);
    }
    h_node[(size_t)node * 128 + d] = acc;
  }
}

__global__ __launch_bounds__(256) void edge_fused_kernel(
    const float* __restrict__ x_edge,
    const int*   __restrict__ eidx,      // [2, E] int32
    const float* __restrict__ W_edge,
    const float* __restrict__ b_edge,
    const float* __restrict__ h_node,
    const float* __restrict__ gamma,
    const float* __restrict__ beta,
    float* __restrict__ out,
    int n_edges)
{
  const int lane = threadIdx.x & 63;
  const int wid  = __builtin_amdgcn_readfirstlane((int)(threadIdx.x >> 6));
  const int gw = blockIdx.x * 4 + wid;
  const int nw = gridDim.x * 4;
  const int d0 = lane, d1 = lane + 64;

  // W_edge rows d0,d1 -> 2x64 floats in VGPRs (resident across edge loop)
  float4 w0[16], w1[16];
  {
    const float4* p0 = (const float4*)(W_edge + (size_t)d0 * 64);
    const float4* p1 = (const float4*)(W_edge + (size_t)d1 * 64);
#pragma unroll
    for (int i = 0; i < 16; ++i) { w0[i] = p0[i]; w1[i] = p1[i]; }
  }
  const float bb0 = b_edge[d0], bb1 = b_edge[d1];
  const float g0  = gamma[d0],  g1  = gamma[d1];
  const float be0 = beta[d0],   be1 = beta[d1];

  for (int e = gw; e < n_edges; e += nw) {
    const float* xr = x_edge + (size_t)e * 64;       // uniform -> s_load
    const int src = eidx[e];                         // uniform scalar loads
    const int dst = eidx[n_edges + e];
    const float* hs = h_node + (size_t)src * 128;
    const float* hd = h_node + (size_t)dst * 128;

    float acc0 = fmaf(0.5f, hs[d0] + hd[d0], bb0);
    float acc1 = fmaf(0.5f, hs[d1] + hd[d1], bb1);
#pragma unroll
    for (int i = 0; i < 16; ++i) {
      const float x0 = xr[4 * i + 0], x1 = xr[4 * i + 1];
      const float x2 = xr[4 * i + 2], x3 = xr[4 * i + 3];
      acc0 = fmaf(w0[i].x, x0, acc0);
      acc0 = fmaf(w0[i].y, x1, acc0);
      acc0 = fmaf(w0[i].z, x2, acc0);
      acc0 = fmaf(w0[i].w, x3, acc0);
      acc1 = fmaf(w1[i].x, x0, acc1);
      acc1 = fmaf(w1[i].y, x1, acc1);
      acc1 = fmaf(w1[i].z, x2, acc1);
      acc1 = fmaf(w1[i].w, x3, acc1);
    }

    // LayerNorm over the 128 dims held by this wave (2 per lane)
    const float tot = wave_sum64(acc0 + acc1);
    const float mu  = tot * (1.0f / 128.0f);
    const float c0 = acc0 - mu, c1 = acc1 - mu;
    const float v  = wave_sum64(c0 * c0 + c1 * c1);
    const float rstd = rsqrtf(v * (1.0f / 128.0f) + 1e-5f);

    float* o = out + (size_t)e * 128;
    o[d0] = fmaf(c0 * rstd, g0, be0);
    o[d1] = fmaf(c1 * rstd, g1, be1);
  }
}

extern "C" void kernel_launch(void* const* d_in, const int* in_sizes, int n_in,
                              void* d_out, int out_size, void* d_ws, size_t ws_size,
                              hipStream_t stream) {
  const float* x_node = (const float*)d_in[0];
  const float* x_edge = (const float*)d_in[1];
  const int*   eidx   = (const int*)  d_in[2];
  const float* W_edge = (const float*)d_in[3];
  const float* b_edge = (const float*)d_in[4];
  const float* W_node = (const float*)d_in[5];
  const float* b_node = (const float*)d_in[6];
  const float* gamma  = (const float*)d_in[7];
  const float* beta   = (const float*)d_in[8];
  float* out = (float*)d_out;

  const int n_nodes = in_sizes[0] / 128;
  const int n_edges = in_sizes[2] / 2;

  float* h_node = (float*)d_ws;
  if (ws_size < (size_t)n_nodes * 128 * sizeof(float)) return;  // loud fail: ws too small

  node_proj_kernel<<<1024, 256, 0, stream>>>(x_node, W_node, b_node, h_node, n_nodes);
  edge_fused_kernel<<<2048, 256, 0, stream>>>(x_edge, eidx, W_edge, b_edge,
                                              h_node, gamma, beta, out, n_edges);
}

// Round 2
// 356.225 us; speedup vs baseline: 3.4360x; 3.4360x over previous
//
#include <hip/hip_runtime.h>

// DualEmbedding v2 — MFMA bf16 GEMMs, per-lane edge ownership.
//
// Kernel A (node): h_node = x_node @ W_node.T + b_node          -> d_ws [N,128] f32
// Kernel B (edge): out = LN(x_edge @ W_edge.T + b_edge + 0.5*(h_node[src]+h_node[dst]))
//
// Both compute C = W @ X^T with v_mfma_f32_16x16x32_bf16:
//   A (M=dims, K)   = W fragments, resident in VGPRs for the whole kernel
//   B (K, N=16 rows)= 16 x-rows, loaded per-lane (32B/lane, 4KB contiguous/wave)
//   C 16x16 tile t:  lane(c=lane&15, g=lane>>4) reg j = C[dim=16t+4g+j][row e0+c]
// => each lane owns ALL 128 dims of ONE row (8 tiles x 4 regs): gather = aligned
//    float4 loads, LayerNorm = local sum + shfl_xor(16) + shfl_xor(32).

typedef __attribute__((ext_vector_type(8))) short bf16x8;
typedef __attribute__((ext_vector_type(4))) float f32x4;

__device__ __forceinline__ short f2bf(float f) {          // RTNE f32->bf16
  unsigned u = __float_as_uint(f);
  u = (u + 0x7FFFu + ((u >> 16) & 1u)) >> 16;
  return (short)u;
}

__device__ __forceinline__ bf16x8 cvt8(const float* __restrict__ p) {
  const f32x4 a = *(const f32x4*)p;
  const f32x4 b = *(const f32x4*)(p + 4);
  bf16x8 r;
  r[0] = f2bf(a[0]); r[1] = f2bf(a[1]); r[2] = f2bf(a[2]); r[3] = f2bf(a[3]);
  r[4] = f2bf(b[0]); r[5] = f2bf(b[1]); r[6] = f2bf(b[2]); r[7] = f2bf(b[3]);
  return r;
}

// ---------------- node projection: h_node = x_node @ W_node.T + b ----------
__global__ __launch_bounds__(256) void node_mfma_kernel(
    const float* __restrict__ x_node,
    const float* __restrict__ W_node,
    const float* __restrict__ b_node,
    float* __restrict__ h_node,
    int n_nodes)
{
  const int lane = threadIdx.x & 63;
  const int c = lane & 15, g = lane >> 4;
  const int gw = blockIdx.x * 4 + (threadIdx.x >> 6);
  const int nw = gridDim.x * 4;
  const int ntiles = (n_nodes + 15) >> 4;

  // A = W_node [128x128]: tile t (rows 16t+c), kslice s: k = 32s+8g+j
  bf16x8 aW[8][4];
#pragma unroll
  for (int t = 0; t < 8; ++t)
#pragma unroll
    for (int s = 0; s < 4; ++s)
      aW[t][s] = cvt8(W_node + (size_t)(16 * t + c) * 128 + 32 * s + 8 * g);

  for (int tile = gw; tile < ntiles; tile += nw) {
    const int n0 = tile << 4;
    const int n = (n0 + c < n_nodes) ? n0 + c : n_nodes - 1;
    const float* xr = x_node + (size_t)n * 128;
    bf16x8 bx[4];
#pragma unroll
    for (int s = 0; s < 4; ++s) bx[s] = cvt8(xr + 32 * s + 8 * g);

    f32x4 acc[8];
#pragma unroll
    for (int t = 0; t < 8; ++t)
      acc[t] = *(const f32x4*)(b_node + 16 * t + 4 * g);
#pragma unroll
    for (int t = 0; t < 8; ++t)
#pragma unroll
      for (int s = 0; s < 4; ++s)
        acc[t] = __builtin_amdgcn_mfma_f32_16x16x32_bf16(aW[t][s], bx[s], acc[t], 0, 0, 0);

    if (n0 + c < n_nodes) {
      float* o = h_node + (size_t)(n0 + c) * 128 + 4 * g;
#pragma unroll
      for (int t = 0; t < 8; ++t) *(f32x4*)(o + 16 * t) = acc[t];
    }
  }
}

// ---------------- fused edge: GEMM + gather + LayerNorm --------------------
__global__ __launch_bounds__(256) void edge_mfma_kernel(
    const float* __restrict__ x_edge,
    const int*   __restrict__ eidx,      // [2, E] int32
    const float* __restrict__ W_edge,
    const float* __restrict__ b_edge,
    const float* __restrict__ h_node,
    const float* __restrict__ gamma,
    const float* __restrict__ beta,
    float* __restrict__ out,
    int n_edges)
{
  const int lane = threadIdx.x & 63;
  const int c = lane & 15, g = lane >> 4;
  const int gw = blockIdx.x * 4 + (threadIdx.x >> 6);
  const int nw = gridDim.x * 4;
  const int ntiles = (n_edges + 15) >> 4;

  // A = W_edge [128x64]: tile t rows 16t+c, kslice s (K=32): k = 32s+8g+j
  bf16x8 aW[8][2];
#pragma unroll
  for (int t = 0; t < 8; ++t)
#pragma unroll
    for (int s = 0; s < 2; ++s)
      aW[t][s] = cvt8(W_edge + (size_t)(16 * t + c) * 64 + 32 * s + 8 * g);

  for (int tile = gw; tile < ntiles; tile += nw) {
    const int e0 = tile << 4;
    const int e = (e0 + c < n_edges) ? e0 + c : n_edges - 1;

    // B fragments: this lane's 32B slice of edge row e
    const float* xr = x_edge + (size_t)e * 64;
    bf16x8 bx0 = cvt8(xr + 8 * g);
    bf16x8 bx1 = cvt8(xr + 32 + 8 * g);

    const int src = eidx[e];
    const int dst = eidx[n_edges + e];
    const float* hs = h_node + (size_t)src * 128 + 4 * g;
    const float* hd = h_node + (size_t)dst * 128 + 4 * g;

    f32x4 acc[8];
#pragma unroll
    for (int t = 0; t < 8; ++t)
      acc[t] = *(const f32x4*)(b_edge + 16 * t + 4 * g);
#pragma unroll
    for (int t = 0; t < 8; ++t) {
      acc[t] = __builtin_amdgcn_mfma_f32_16x16x32_bf16(aW[t][0], bx0, acc[t], 0, 0, 0);
      acc[t] = __builtin_amdgcn_mfma_f32_16x16x32_bf16(aW[t][1], bx1, acc[t], 0, 0, 0);
    }

    // + 0.5*(h_node[src] + h_node[dst]) on this lane's 32 dims
#pragma unroll
    for (int t = 0; t < 8; ++t) {
      const f32x4 vs = *(const f32x4*)(hs + 16 * t);
      const f32x4 vd = *(const f32x4*)(hd + 16 * t);
      acc[t] += (vs + vd) * 0.5f;
    }

    // LayerNorm over this lane's edge; dims split across lanes {c, c+16, c+32, c+48}
    float s1 = 0.f;
#pragma unroll
    for (int t = 0; t < 8; ++t)
      s1 += (acc[t][0] + acc[t][1]) + (acc[t][2] + acc[t][3]);
    s1 += __shfl_xor(s1, 16, 64);
    s1 += __shfl_xor(s1, 32, 64);
    const float mu = s1 * (1.f / 128.f);

    float s2 = 0.f;
#pragma unroll
    for (int t = 0; t < 8; ++t)
#pragma unroll
      for (int j = 0; j < 4; ++j) {
        const float d = acc[t][j] - mu;
        acc[t][j] = d;
        s2 = fmaf(d, d, s2);
      }
    s2 += __shfl_xor(s2, 16, 64);
    s2 += __shfl_xor(s2, 32, 64);
    const float rstd = rsqrtf(s2 * (1.f / 128.f) + 1e-5f);

    if (e0 + c < n_edges) {
      float* o = out + (size_t)(e0 + c) * 128 + 4 * g;
#pragma unroll
      for (int t = 0; t < 8; ++t) {
        const f32x4 gg = *(const f32x4*)(gamma + 16 * t + 4 * g);
        const f32x4 be = *(const f32x4*)(beta + 16 * t + 4 * g);
        f32x4 r;
#pragma unroll
        for (int j = 0; j < 4; ++j) r[j] = fmaf(acc[t][j] * rstd, gg[j], be[j]);
        *(f32x4*)(o + 16 * t) = r;
      }
    }
  }
}

extern "C" void kernel_launch(void* const* d_in, const int* in_sizes, int n_in,
                              void* d_out, int out_size, void* d_ws, size_t ws_size,
                              hipStream_t stream) {
  const float* x_node = (const float*)d_in[0];
  const float* x_edge = (const float*)d_in[1];
  const int*   eidx   = (const int*)  d_in[2];
  const float* W_edge = (const float*)d_in[3];
  const float* b_edge = (const float*)d_in[4];
  const float* W_node = (const float*)d_in[5];
  const float* b_node = (const float*)d_in[6];
  const float* gamma  = (const float*)d_in[7];
  const float* beta   = (const float*)d_in[8];
  float* out = (float*)d_out;

  const int n_nodes = in_sizes[0] / 128;
  const int n_edges = in_sizes[2] / 2;

  float* h_node = (float*)d_ws;
  if (ws_size < (size_t)n_nodes * 128 * sizeof(float)) return;  // ws too small

  node_mfma_kernel<<<512, 256, 0, stream>>>(x_node, W_node, b_node, h_node, n_nodes);
  edge_mfma_kernel<<<1024, 256, 0, stream>>>(x_edge, eidx, W_edge, b_edge,
                                             h_node, gamma, beta, out, n_edges);
}

// Round 3
// 295.269 us; speedup vs baseline: 4.1454x; 1.2064x over previous
//
#include <hip/hip_runtime.h>

// DualEmbedding v3 — MFMA bf16 GEMMs + bf16 permuted h_node + pipelined gather.
//
// Kernel A (node): h_node_bf16[node][g*32+t*4+j] = (x_node @ W_node.T + b)[node][16t+4g+j]
//   (permuted, bf16: each edge-kernel lane's 32 dims are one contiguous 64B chunk)
// Kernel B (edge): out = LN(x_edge @ W_edge.T + b_edge + 0.5*(h[src]+h[dst]))
//
// MFMA mapping (16x16x32 bf16): C tile t, lane(c=lane&15,g=lane>>4), reg j =
//   C[dim=16t+4g+j][row base+c]  -> each lane owns all 128 dims of ONE row.

typedef __attribute__((ext_vector_type(8))) short bf16x8;
typedef __attribute__((ext_vector_type(4))) float f32x4;

__device__ __forceinline__ short f2bf(float f) {          // RTNE f32->bf16
  unsigned u = __float_as_uint(f);
  u = (u + 0x7FFFu + ((u >> 16) & 1u)) >> 16;
  return (short)u;
}
__device__ __forceinline__ float bf2f(short s) {
  return __uint_as_float(((unsigned)(unsigned short)s) << 16);
}
__device__ __forceinline__ bf16x8 cvt8(const float* __restrict__ p) {
  const f32x4 a = *(const f32x4*)p;
  const f32x4 b = *(const f32x4*)(p + 4);
  bf16x8 r;
  r[0] = f2bf(a[0]); r[1] = f2bf(a[1]); r[2] = f2bf(a[2]); r[3] = f2bf(a[3]);
  r[4] = f2bf(b[0]); r[5] = f2bf(b[1]); r[6] = f2bf(b[2]); r[7] = f2bf(b[3]);
  return r;
}

// ---------------- node projection -> permuted bf16 table -------------------
__global__ __launch_bounds__(256) void node_mfma_kernel(
    const float* __restrict__ x_node,
    const float* __restrict__ W_node,
    const float* __restrict__ b_node,
    short* __restrict__ h_node,          // [N][128] bf16, permuted
    int n_nodes)
{
  const int lane = threadIdx.x & 63;
  const int c = lane & 15, g = lane >> 4;
  const int gw = blockIdx.x * 4 + (threadIdx.x >> 6);
  const int nw = gridDim.x * 4;
  const int ntiles = (n_nodes + 15) >> 4;

  bf16x8 aW[8][4];
#pragma unroll
  for (int t = 0; t < 8; ++t)
#pragma unroll
    for (int s = 0; s < 4; ++s)
      aW[t][s] = cvt8(W_node + (size_t)(16 * t + c) * 128 + 32 * s + 8 * g);

  for (int tile = gw; tile < ntiles; tile += nw) {
    const int n0 = tile << 4;
    const int n = (n0 + c < n_nodes) ? n0 + c : n_nodes - 1;
    const float* xr = x_node + (size_t)n * 128;
    bf16x8 bx[4];
#pragma unroll
    for (int s = 0; s < 4; ++s) bx[s] = cvt8(xr + 32 * s + 8 * g);

    f32x4 acc[8];
#pragma unroll
    for (int t = 0; t < 8; ++t)
      acc[t] = *(const f32x4*)(b_node + 16 * t + 4 * g);
#pragma unroll
    for (int t = 0; t < 8; ++t)
#pragma unroll
      for (int s = 0; s < 4; ++s)
        acc[t] = __builtin_amdgcn_mfma_f32_16x16x32_bf16(aW[t][s], bx[s], acc[t], 0, 0, 0);

    if (n0 + c < n_nodes) {
      short* o = h_node + (size_t)(n0 + c) * 128 + g * 32;   // contiguous 64B
#pragma unroll
      for (int k = 0; k < 4; ++k) {
        bf16x8 v;
#pragma unroll
        for (int j = 0; j < 4; ++j) {
          v[j]     = f2bf(acc[2 * k][j]);
          v[4 + j] = f2bf(acc[2 * k + 1][j]);
        }
        *(bf16x8*)(o + 8 * k) = v;
      }
    }
  }
}

// ---------------- fused edge: GEMM + gather + LayerNorm --------------------
__global__ __launch_bounds__(256) void edge_mfma_kernel(
    const float* __restrict__ x_edge,
    const int*   __restrict__ eidx,      // [2, E] int32
    const float* __restrict__ W_edge,
    const float* __restrict__ b_edge,
    const short* __restrict__ h_node,    // permuted bf16
    const float* __restrict__ gamma,
    const float* __restrict__ beta,
    float* __restrict__ out,
    int n_edges)
{
  const int lane = threadIdx.x & 63;
  const int c = lane & 15, g = lane >> 4;
  const int gw = blockIdx.x * 4 + (threadIdx.x >> 6);
  const int nw = gridDim.x * 4;
  const int ntiles = (n_edges + 15) >> 4;

  bf16x8 aW[8][2];
#pragma unroll
  for (int t = 0; t < 8; ++t)
#pragma unroll
    for (int s = 0; s < 2; ++s)
      aW[t][s] = cvt8(W_edge + (size_t)(16 * t + c) * 64 + 32 * s + 8 * g);

  int tile = gw;
  bf16x8 bx0, bx1;
  int src = 0, dst = 0;
  if (tile < ntiles) {                       // prologue: loads for first tile
    const int e = (tile * 16 + c < n_edges) ? tile * 16 + c : n_edges - 1;
    const float* xr = x_edge + (size_t)e * 64;
    bx0 = cvt8(xr + 8 * g);
    bx1 = cvt8(xr + 32 + 8 * g);
    src = eidx[e];
    dst = eidx[n_edges + e];
  }

  for (; tile < ntiles; tile += nw) {
    // 1) issue this tile's gathers (addresses ready from previous iteration)
    const short* hs = h_node + (size_t)src * 128 + g * 32;
    const short* hd = h_node + (size_t)dst * 128 + g * 32;
    bf16x8 vs[4], vd[4];
#pragma unroll
    for (int k = 0; k < 4; ++k) {
      vs[k] = *(const bf16x8*)(hs + 8 * k);
      vd[k] = *(const bf16x8*)(hd + 8 * k);
    }

    // 2) prefetch next tile's x-fragments and indices (clamped, branchless)
    const int ntile = (tile + nw < ntiles) ? tile + nw : ntiles - 1;
    const int en = (ntile * 16 + c < n_edges) ? ntile * 16 + c : n_edges - 1;
    const float* xrn = x_edge + (size_t)en * 64;
    const bf16x8 bxn0 = cvt8(xrn + 8 * g);
    const bf16x8 bxn1 = cvt8(xrn + 32 + 8 * g);
    const int srcn = eidx[en];
    const int dstn = eidx[n_edges + en];

    // 3) GEMM for this tile
    f32x4 acc[8];
#pragma unroll
    for (int t = 0; t < 8; ++t)
      acc[t] = *(const f32x4*)(b_edge + 16 * t + 4 * g);
#pragma unroll
    for (int t = 0; t < 8; ++t) {
      acc[t] = __builtin_amdgcn_mfma_f32_16x16x32_bf16(aW[t][0], bx0, acc[t], 0, 0, 0);
      acc[t] = __builtin_amdgcn_mfma_f32_16x16x32_bf16(aW[t][1], bx1, acc[t], 0, 0, 0);
    }

    // 4) add 0.5*(h[src]+h[dst])  (chunk k = tiles 2k,2k+1, j-fast)
#pragma unroll
    for (int k = 0; k < 4; ++k)
#pragma unroll
      for (int j = 0; j < 4; ++j) {
        acc[2 * k][j]     += 0.5f * (bf2f(vs[k][j])     + bf2f(vd[k][j]));
        acc[2 * k + 1][j] += 0.5f * (bf2f(vs[k][4 + j]) + bf2f(vd[k][4 + j]));
      }

    // 5) LayerNorm (dims of this edge split over lanes c, c+16, c+32, c+48)
    float s1 = 0.f;
#pragma unroll
    for (int t = 0; t < 8; ++t)
      s1 += (acc[t][0] + acc[t][1]) + (acc[t][2] + acc[t][3]);
    s1 += __shfl_xor(s1, 16, 64);
    s1 += __shfl_xor(s1, 32, 64);
    const float mu = s1 * (1.f / 128.f);

    float s2 = 0.f;
#pragma unroll
    for (int t = 0; t < 8; ++t)
#pragma unroll
      for (int j = 0; j < 4; ++j) {
        const float d = acc[t][j] - mu;
        acc[t][j] = d;
        s2 = fmaf(d, d, s2);
      }
    s2 += __shfl_xor(s2, 16, 64);
    s2 += __shfl_xor(s2, 32, 64);
    const float rstd = rsqrtf(s2 * (1.f / 128.f) + 1e-5f);

    const int e0 = tile << 4;
    if (e0 + c < n_edges) {
      float* o = out + (size_t)(e0 + c) * 128 + 4 * g;
#pragma unroll
      for (int t = 0; t < 8; ++t) {
        const f32x4 gg = *(const f32x4*)(gamma + 16 * t + 4 * g);
        const f32x4 be = *(const f32x4*)(beta + 16 * t + 4 * g);
        f32x4 r;
#pragma unroll
        for (int j = 0; j < 4; ++j) r[j] = fmaf(acc[t][j] * rstd, gg[j], be[j]);
        *(f32x4*)(o + 16 * t) = r;
      }
    }

    // 6) rotate pipeline registers
    bx0 = bxn0; bx1 = bxn1; src = srcn; dst = dstn;
  }
}

extern "C" void kernel_launch(void* const* d_in, const int* in_sizes, int n_in,
                              void* d_out, int out_size, void* d_ws, size_t ws_size,
                              hipStream_t stream) {
  const float* x_node = (const float*)d_in[0];
  const float* x_edge = (const float*)d_in[1];
  const int*   eidx   = (const int*)  d_in[2];
  const float* W_edge = (const float*)d_in[3];
  const float* b_edge = (const float*)d_in[4];
  const float* W_node = (const float*)d_in[5];
  const float* b_node = (const float*)d_in[6];
  const float* gamma  = (const float*)d_in[7];
  const float* beta   = (const float*)d_in[8];
  float* out = (float*)d_out;

  const int n_nodes = in_sizes[0] / 128;
  const int n_edges = in_sizes[2] / 2;

  short* h_node = (short*)d_ws;
  if (ws_size < (size_t)n_nodes * 128 * sizeof(short)) return;  // ws too small

  node_mfma_kernel<<<512, 256, 0, stream>>>(x_node, W_node, b_node, h_node, n_nodes);
  edge_mfma_kernel<<<2048, 256, 0, stream>>>(x_edge, eidx, W_edge, b_edge,
                                             h_node, gamma, beta, out, n_edges);
}

// Round 4
// 275.816 us; speedup vs baseline: 4.4377x; 1.0705x over previous
//
#include <hip/hip_runtime.h>

// DualEmbedding v4 — edge kernel: W in LDS (swizzled), gather double-buffered
// one full iteration ahead (register A/B sets, manual unroll-2).
//
// Kernel A (node): h_node_bf16[node][g*32+t*4+j] = (x_node @ W_node.T + b)[node][16t+4g+j]
// Kernel B (edge): out = LN(x_edge @ W_edge.T + b_edge + 0.5*(h[src]+h[dst]))
//
// MFMA mapping (16x16x32 bf16): C tile t, lane(c=lane&15,g=lane>>4), reg j =
//   C[dim=16t+4g+j][row base+c]  -> each lane owns all 128 dims of ONE row.

typedef __attribute__((ext_vector_type(8))) short bf16x8;
typedef __attribute__((ext_vector_type(4))) float f32x4;

__device__ __forceinline__ short f2bf(float f) {          // RTNE f32->bf16
  unsigned u = __float_as_uint(f);
  u = (u + 0x7FFFu + ((u >> 16) & 1u)) >> 16;
  return (short)u;
}
__device__ __forceinline__ float bf2f(short s) {
  return __uint_as_float(((unsigned)(unsigned short)s) << 16);
}
__device__ __forceinline__ bf16x8 cvt8(const float* __restrict__ p) {
  const f32x4 a = *(const f32x4*)p;
  const f32x4 b = *(const f32x4*)(p + 4);
  bf16x8 r;
  r[0] = f2bf(a[0]); r[1] = f2bf(a[1]); r[2] = f2bf(a[2]); r[3] = f2bf(a[3]);
  r[4] = f2bf(b[0]); r[5] = f2bf(b[1]); r[6] = f2bf(b[2]); r[7] = f2bf(b[3]);
  return r;
}

// ---------------- node projection -> permuted bf16 table -------------------
__global__ __launch_bounds__(256) void node_mfma_kernel(
    const float* __restrict__ x_node,
    const float* __restrict__ W_node,
    const float* __restrict__ b_node,
    short* __restrict__ h_node,          // [N][128] bf16, permuted
    int n_nodes)
{
  const int lane = threadIdx.x & 63;
  const int c = lane & 15, g = lane >> 4;
  const int gw = blockIdx.x * 4 + (threadIdx.x >> 6);
  const int nw = gridDim.x * 4;
  const int ntiles = (n_nodes + 15) >> 4;

  bf16x8 aW[8][4];
#pragma unroll
  for (int t = 0; t < 8; ++t)
#pragma unroll
    for (int s = 0; s < 4; ++s)
      aW[t][s] = cvt8(W_node + (size_t)(16 * t + c) * 128 + 32 * s + 8 * g);

  for (int tile = gw; tile < ntiles; tile += nw) {
    const int n0 = tile << 4;
    const int n = (n0 + c < n_nodes) ? n0 + c : n_nodes - 1;
    const float* xr = x_node + (size_t)n * 128;
    bf16x8 bx[4];
#pragma unroll
    for (int s = 0; s < 4; ++s) bx[s] = cvt8(xr + 32 * s + 8 * g);

    f32x4 acc[8];
#pragma unroll
    for (int t = 0; t < 8; ++t)
      acc[t] = *(const f32x4*)(b_node + 16 * t + 4 * g);
#pragma unroll
    for (int t = 0; t < 8; ++t)
#pragma unroll
      for (int s = 0; s < 4; ++s)
        acc[t] = __builtin_amdgcn_mfma_f32_16x16x32_bf16(aW[t][s], bx[s], acc[t], 0, 0, 0);

    if (n0 + c < n_nodes) {
      short* o = h_node + (size_t)(n0 + c) * 128 + g * 32;   // contiguous 64B
#pragma unroll
      for (int k = 0; k < 4; ++k) {
        bf16x8 v;
#pragma unroll
        for (int j = 0; j < 4; ++j) {
          v[j]     = f2bf(acc[2 * k][j]);
          v[4 + j] = f2bf(acc[2 * k + 1][j]);
        }
        *(bf16x8*)(o + 8 * k) = v;
      }
    }
  }
}

// ---------------- fused edge: GEMM + gather + LayerNorm --------------------
__global__ __launch_bounds__(256) void edge_mfma_kernel(
    const float* __restrict__ x_edge,
    const int*   __restrict__ eidx,      // [2, E] int32
    const float* __restrict__ W_edge,
    const float* __restrict__ b_edge,
    const short* __restrict__ h_node,    // permuted bf16
    const float* __restrict__ gamma,
    const float* __restrict__ beta,
    float* __restrict__ out,
    int n_edges)
{
  // LDS: W_edge bf16, XOR-swizzled (slot sigma of row r stored at sigma^(r&7));
  // plus bias/gamma/beta.
  __shared__ short Wlds[8192];          // 128 rows x 64 bf16 = 16 KB
  __shared__ float plds[384];           // bias | gamma | beta

  const int tid = threadIdx.x;
  {
    const int r = tid >> 1, h = tid & 1;
    const float* wr = W_edge + (size_t)r * 64 + 32 * h;
#pragma unroll
    for (int q = 0; q < 4; ++q) {
      const bf16x8 v = cvt8(wr + 8 * q);
      const int slot = (4 * h + q) ^ (r & 7);
      *(bf16x8*)(&Wlds[r * 64 + slot * 8]) = v;
    }
    if (tid < 128) {
      plds[tid]       = b_edge[tid];
      plds[128 + tid] = gamma[tid];
      plds[256 + tid] = beta[tid];
    }
  }
  __syncthreads();

  const int lane = threadIdx.x & 63;
  const int c = lane & 15, g = lane >> 4;
  const int gw = blockIdx.x * 4 + (threadIdx.x >> 6);
  const int nw = gridDim.x * 4;
  const int ntiles = (n_edges + 15) >> 4;

  // per-lane swizzled LDS offsets for A fragments (short indices), s in {0,1}
  const int w0off = c * 64 + ((g) ^ (c & 7)) * 8;
  const int w1off = c * 64 + ((4 + g) ^ (c & 7)) * 8;

  if (gw >= ntiles) return;

  // ---- pipeline helpers -------------------------------------------------
  auto LOADIDX = [&](int tile, int& src, int& dst) {
    const int e = (tile * 16 + c < n_edges) ? tile * 16 + c : n_edges - 1;
    src = eidx[e];
    dst = eidx[n_edges + e];
  };
  auto LOADX = [&](int tile, bf16x8& b0, bf16x8& b1) {
    const int e = (tile * 16 + c < n_edges) ? tile * 16 + c : n_edges - 1;
    const float* xr = x_edge + (size_t)e * 64;
    b0 = cvt8(xr + 8 * g);
    b1 = cvt8(xr + 32 + 8 * g);
  };
  auto GATHER = [&](int src, int dst, bf16x8* vs, bf16x8* vd) {
    const short* hs = h_node + (size_t)src * 128 + g * 32;
    const short* hd = h_node + (size_t)dst * 128 + g * 32;
#pragma unroll
    for (int k = 0; k < 4; ++k) {
      vs[k] = *(const bf16x8*)(hs + 8 * k);
      vd[k] = *(const bf16x8*)(hd + 8 * k);
    }
  };
  auto COMPUTE = [&](int tile, bf16x8 b0, bf16x8 b1, bf16x8* vs, bf16x8* vd) {
    f32x4 acc[8];
    // acc = bias + 0.5*(h[src]+h[dst])   (endpoints first: vs/vd die early)
#pragma unroll
    for (int k = 0; k < 4; ++k)
#pragma unroll
      for (int j = 0; j < 4; ++j) {
        acc[2 * k][j]     = plds[16 * (2 * k) + 4 * g + j]
                          + 0.5f * (bf2f(vs[k][j]) + bf2f(vd[k][j]));
        acc[2 * k + 1][j] = plds[16 * (2 * k + 1) + 4 * g + j]
                          + 0.5f * (bf2f(vs[k][4 + j]) + bf2f(vd[k][4 + j]));
      }
    // GEMM: A fragments from swizzled LDS
#pragma unroll
    for (int t = 0; t < 8; ++t) {
      const bf16x8 a0 = *(const bf16x8*)(&Wlds[t * 1024 + w0off]);
      const bf16x8 a1 = *(const bf16x8*)(&Wlds[t * 1024 + w1off]);
      acc[t] = __builtin_amdgcn_mfma_f32_16x16x32_bf16(a0, b0, acc[t], 0, 0, 0);
      acc[t] = __builtin_amdgcn_mfma_f32_16x16x32_bf16(a1, b1, acc[t], 0, 0, 0);
    }
    // LayerNorm (dims of one edge split over lanes c, c+16, c+32, c+48)
    float s1 = 0.f;
#pragma unroll
    for (int t = 0; t < 8; ++t)
      s1 += (acc[t][0] + acc[t][1]) + (acc[t][2] + acc[t][3]);
    s1 += __shfl_xor(s1, 16, 64);
    s1 += __shfl_xor(s1, 32, 64);
    const float mu = s1 * (1.f / 128.f);

    float s2 = 0.f;
#pragma unroll
    for (int t = 0; t < 8; ++t)
#pragma unroll
      for (int j = 0; j < 4; ++j) {
        const float d = acc[t][j] - mu;
        acc[t][j] = d;
        s2 = fmaf(d, d, s2);
      }
    s2 += __shfl_xor(s2, 16, 64);
    s2 += __shfl_xor(s2, 32, 64);
    const float rstd = rsqrtf(s2 * (1.f / 128.f) + 1e-5f);

    if (tile * 16 + c < n_edges) {
      float* o = out + (size_t)(tile * 16 + c) * 128 + 4 * g;
#pragma unroll
      for (int t = 0; t < 8; ++t) {
        f32x4 r;
#pragma unroll
        for (int j = 0; j < 4; ++j)
          r[j] = fmaf(acc[t][j] * rstd, plds[128 + 16 * t + 4 * g + j],
                      plds[256 + 16 * t + 4 * g + j]);
        *(f32x4*)(o + 16 * t) = r;
      }
    }
  };

  // ---- software pipeline: gather issued one full tile ahead --------------
  bf16x8 bxA0, bxA1, bxB0, bxB1;
  bf16x8 vsA[4], vdA[4], vsB[4], vdB[4];
  int srcA, dstA, srcB, dstB;

  // prologue
  LOADIDX(gw, srcA, dstA);
  LOADX(gw, bxA0, bxA1);
  GATHER(srcA, dstA, vsA, vdA);          // gathers for tile gw
  LOADIDX(gw + nw, srcB, dstB);          // clamped if past end
  LOADX(gw + nw, bxB0, bxB1);

  int t = gw;
  for (;;) {
    // body A: compute tile t; issue gathers for t+nw; prefetch t+2*nw into A
    GATHER(srcB, dstB, vsB, vdB);
    LOADIDX(t + 2 * nw, srcA, dstA);
    COMPUTE(t, bxA0, bxA1, vsA, vdA);
    LOADX(t + 2 * nw, bxA0, bxA1);
    t += nw;
    if (t >= ntiles) break;

    // body B: mirror
    GATHER(srcA, dstA, vsA, vdA);
    LOADIDX(t + 2 * nw, srcB, dstB);
    COMPUTE(t, bxB0, bxB1, vsB, vdB);
    LOADX(t + 2 * nw, bxB0, bxB1);
    t += nw;
    if (t >= ntiles) break;
  }
}

extern "C" void kernel_launch(void* const* d_in, const int* in_sizes, int n_in,
                              void* d_out, int out_size, void* d_ws, size_t ws_size,
                              hipStream_t stream) {
  const float* x_node = (const float*)d_in[0];
  const float* x_edge = (const float*)d_in[1];
  const int*   eidx   = (const int*)  d_in[2];
  const float* W_edge = (const float*)d_in[3];
  const float* b_edge = (const float*)d_in[4];
  const float* W_node = (const float*)d_in[5];
  const float* b_node = (const float*)d_in[6];
  const float* gamma  = (const float*)d_in[7];
  const float* beta   = (const float*)d_in[8];
  float* out = (float*)d_out;

  const int n_nodes = in_sizes[0] / 128;
  const int n_edges = in_sizes[2] / 2;

  short* h_node = (short*)d_ws;
  if (ws_size < (size_t)n_nodes * 128 * sizeof(short)) return;  // ws too small

  node_mfma_kernel<<<512, 256, 0, stream>>>(x_node, W_node, b_node, h_node, n_nodes);
  edge_mfma_kernel<<<2048, 256, 0, stream>>>(x_edge, eidx, W_edge, b_edge,
                                             h_node, gamma, beta, out, n_edges);
}